// Round 2
// baseline (246.790 us; speedup 1.0000x reference)
//
#include <hip/hip_runtime.h>
#include <math.h>

// UpPolyAct: out = c0 + c1*x + 0.25*c2*( z_ee + V + W )
//   R = X M^T, L = M X, OO = L M^T
//   z_eo=(R+corr)^2, z_oe=(L+corr)^2, z_oo=OO^2, z_ee=(E X E)^2
//   U = z_oe + z_oo M,  V = M^T U,  W = z_eo M
// MFMA plan (32x32x16 bf16, 1 tile/wave, T-domain through U):
//   Rt = M X^T        A=tab(gr,rb)  B=Xr rows
//   Lt = X^T M^T      A=Xc rows     B=tab(gr,cb)
//   OOt = M Lt        A=tab(gr,rb)  B=Lr rows      (Lr = L row-major, T-write)
//   Ut = zoeT + M^T zooT   A=tab(g,rb)  B=Zoo rows (acc init = z_oeT regs)
//   W  = z_eo M       A=Zeo rows    B=tab(g,cb)    (untransposed)
//   V  = M^T U        A=tab(g,rb)   B=UtR rows     (untransposed)
//
// R2 changes vs R1:
//  - grid = 768 (exact 3-blocks/CU residency, zero block-wave tail),
//    bijective CHUNKED channel assignment (contiguous chunks per block)
//  - x loaded in MFMA-fragment order into registers; epilogue uses the held
//    regs (no global re-read, no Xr LDS re-read; bf2f(f2bf(x)) bit-identical)
//  - cross-channel register prefetch issued after B1 (hidden under M1+MFMA)
//  - loop-end barrier removed (epilogue no longer reads Xr/XcZ; B1 orders
//    the tvec/uvec rewrite)

typedef short short8 __attribute__((ext_vector_type(8)));
typedef float f32x16 __attribute__((ext_vector_type(16)));

#define LSH 68  // bf16 LDS row stride (68 shorts = 136 B, rows 8B-aligned)

__device__ __forceinline__ short f2bf(float f) {
  unsigned u = __float_as_uint(f);
  u += 0x7FFFu + ((u >> 16) & 1u);
  return (short)(u >> 16);
}
__device__ __forceinline__ float bf2f(short s) {
  return __uint_as_float(((unsigned)(unsigned short)s) << 16);
}
__device__ __forceinline__ short8 ldrow(const short* p) {
  union { unsigned u[4]; short8 s; } v;
  const uint2 lo = *(const uint2*)p;
  const uint2 hi = *(const uint2*)(p + 4);
  v.u[0] = lo.x; v.u[1] = lo.y; v.u[2] = hi.x; v.u[3] = hi.y;
  return v.s;
}

__global__ __launch_bounds__(256, 3) void uppolyact_kernel(
    const float* __restrict__ x, const float* __restrict__ coef,
    float* __restrict__ out, int nch) {
  __shared__ __align__(16) short Xr[64 * LSH];    // X row-major bf16
  __shared__ __align__(16) short XcZ[64 * LSH];   // X^T row-major, then z_eo row-major
  __shared__ __align__(16) short LrU[64 * LSH];   // L row-major, then U^T row-major
  __shared__ __align__(16) short Zoo[64 * LSH];   // z_oo row-major
  __shared__ __align__(16) short ftab[16 * 64 * 8];  // M fragments, slot=(t*2+blk)*4+kk
  __shared__ float g64[64];
  __shared__ float tvec[64], uvec[64], sRv[64], Luv[64];
  __shared__ float sigv;

  const int tid = threadIdx.x;
  const int lane = tid & 63;
  const int w = tid >> 6;
  const int q = lane >> 5;
  const int l31 = lane & 31;
  const int rb = w >> 1, cb = w & 1;
  const int jcol = cb * 32 + l31;  // this thread's fixed output column

  // ---- bijective chunked channel range for this block ----
  const int nb = gridDim.x;
  const int bq = nch / nb, br = nch % nb;
  int ch0, cnt;
  if ((int)blockIdx.x < br) {
    ch0 = blockIdx.x * (bq + 1);
    cnt = bq + 1;
  } else {
    ch0 = br * (bq + 1) + (blockIdx.x - br) * bq;
    cnt = bq;
  }

  // ---- issue first channel's x loads (fragment order) before table build ----
  float xcur[16];
  {
    const float* xb0 = x + (size_t)ch0 * 4096;
#pragma unroll
    for (int r = 0; r < 16; ++r) {
      const int irow = rb * 32 + (r & 3) + 4 * q + 8 * (r >> 2);
      xcur[r] = xb0[irow * 64 + jcol];
    }
  }

  // ---- once per block: g table (bit-identical to baseline) ----
  if (tid < 64) {
    const int d = 2 * tid + 1;
    float s = 1.0f;
    for (int k = 1; k <= 32; ++k) {
      const int qq = (k * d) & 127;
      s += 2.0f * cosf((float)M_PI * (1.0f / 64.0f) * (float)qq);
    }
    g64[tid] = s * (1.0f / 64.0f);
  }
  __syncthreads();

  // ---- once per block: M fragment table ----
#pragma unroll
  for (int e = 0; e < 4; ++e) {
    const int entry = tid + 256 * e;  // 0..1023
    const int s_ = entry >> 6, ln = entry & 63;
    const int t_ = s_ >> 3, blk = (s_ >> 2) & 1, kk = s_ & 3;
    const int basei = kk * 16 + (ln >> 5) * 8 - (ln & 31) - 32 * blk;
    short* dst = &ftab[(s_ * 64 + ln) * 8];
#pragma unroll
    for (int j = 0; j < 8; ++j) {
      const int i0 = basei + j;
      const int idx = t_ ? ((-i0) & 63) : (i0 & 63);
      dst[j] = f2bf(g64[idx]);
    }
  }

  const float c0 = coef[0], c1 = coef[1];
  const float c2q = 0.25f * coef[2];

  for (int ci = 0; ci < cnt; ++ci) {
    const int ch = ch0 + ci;
    float* ob = out + (size_t)ch * 4096;

    // ---- P0: xcur regs -> Xr + Xc (bf16) ----
#pragma unroll
    for (int r = 0; r < 16; ++r) {
      const int irow = rb * 32 + (r & 3) + 4 * q + 8 * (r >> 2);
      const short bv = f2bf(xcur[r]);
      Xr[irow * LSH + jcol] = bv;
      XcZ[jcol * LSH + irow] = bv;
    }
    __syncthreads();  // B1 (also publishes ftab on first iteration)

    // ---- prefetch next channel into regs (drained at B2; hidden by M1+MFMA)
    float xnxt[16];
    if (ci + 1 < cnt) {
      const float* xnb = x + (size_t)(ch + 1) * 4096;
#pragma unroll
      for (int r = 0; r < 16; ++r) {
        const int irow = rb * 32 + (r & 3) + 4 * q + 8 * (r >> 2);
        xnxt[r] = xnb[irow * 64 + jcol];
      }
    }

    // ---- M1: tvec/uvec with all 256 threads (vectorized) ----
    // tvec[j] = sum_i sign_i X[i][j]   (rows of XcZ, contiguous)
    // uvec[i] = sum_j X[i][j] sign_j   (rows of Xr, contiguous)
    {
      const int o = tid >> 1, h = tid & 1;  // o: output 0..127, h: half
      const short* src = (o < 64) ? &XcZ[o * LSH + 32 * h]
                                  : &Xr[(o - 64) * LSH + 32 * h];
      float acc = 0.0f;
#pragma unroll
      for (int p = 0; p < 4; ++p) {
        const short8 v = ldrow(src + 8 * p);
#pragma unroll
        for (int j = 0; j < 8; ++j) {
          const float f = bf2f(v[j]);
          acc += (j & 1) ? -f : f;  // element index 32h+8p+j, parity = j&1
        }
      }
      acc += __shfl_xor(acc, 1);
      if (h == 0) {
        if (o < 64) tvec[o] = acc; else uvec[o - 64] = acc;
      }
    }

    // ---- MFMA Rt, Lt (independent of M1 results) ----
    f32x16 Rt, Lt;
#pragma unroll
    for (int r = 0; r < 16; ++r) { Rt[r] = 0.0f; Lt[r] = 0.0f; }
#pragma unroll
    for (int kk = 0; kk < 4; ++kk) {
      const short8 aR = *(const short8*)&ftab[(((2 + rb) * 4 + kk) * 64 + lane) * 8];  // (gr,rb)
      const short8 bR = ldrow(&Xr[(cb * 32 + l31) * LSH + kk * 16 + q * 8]);
      Rt = __builtin_amdgcn_mfma_f32_32x32x16_bf16(aR, bR, Rt, 0, 0, 0);
      const short8 aL = ldrow(&XcZ[(rb * 32 + l31) * LSH + kk * 16 + q * 8]);
      const short8 bL = *(const short8*)&ftab[(((2 + cb) * 4 + kk) * 64 + lane) * 8];  // (gr,cb)
      Lt = __builtin_amdgcn_mfma_f32_32x32x16_bf16(aL, bL, Lt, 0, 0, 0);
    }
    __syncthreads();  // B2: tvec/uvec visible; Xr/XcZ reads of this phase done

    // ---- M2: sRv/Luv with all 256 threads; sigv on wave 0 ----
    // sRv[j] = sum_m tvec[m]*g64[(j-m)&63] ; Luv[i] = sum_m g64[(i-m)&63]*uvec[m]
    {
      const int o = tid >> 1, h = tid & 1;
      const int o63 = o & 63;
      const float* vsrc = (o < 64) ? tvec : uvec;  // wave-uniform select
      float acc = 0.0f;
#pragma unroll
      for (int p = 0; p < 32; ++p) {
        const int m = 32 * h + p;
        acc += vsrc[m] * g64[(o63 - m) & 63];
      }
      acc += __shfl_xor(acc, 1);
      if (h == 0) {
        if (o < 64) sRv[o] = acc; else Luv[o - 64] = acc;
      }
    }
    if (w == 0) {  // sigv = s^T X s = sum_j sign_j * tvec[j]
      float sv = (lane & 1) ? -tvec[lane] : tvec[lane];
#pragma unroll
      for (int d_ = 1; d_ < 64; d_ <<= 1) sv += __shfl_xor(sv, d_);
      if (lane == 0) sigv = sv;
    }
    __syncthreads();  // B3

    // ---- P2: z_eoT -> XcZ (T-write), Lt -> LrU (T-write), z_oeT regs ----
    float zoe[16];
#pragma unroll
    for (int r = 0; r < 16; ++r) {
      const int jrow = rb * 32 + (r & 3) + 4 * q + 8 * (r >> 2);
      const int icol = cb * 32 + l31;
      const float sgi = (icol & 1) ? -1.0f : 1.0f;
      const float sgj = (jrow & 1) ? -1.0f : 1.0f;
      const float veo = Rt[r] + sgi * sRv[jrow] * (1.0f / 64.0f);
      XcZ[icol * LSH + jrow] = f2bf(veo * veo);   // z_eo[i][j]
      LrU[icol * LSH + jrow] = f2bf(Lt[r]);       // L[i][j]
      const float voe = Lt[r] + Luv[icol] * sgj * (1.0f / 64.0f);
      zoe[r] = voe * voe;                         // z_oeT[j][i] (C-layout)
    }
    __syncthreads();  // B4

    // ---- P3: OOt = M*Lt ; z_oo -> Zoo (T-write) ----
    f32x16 OOt;
#pragma unroll
    for (int r = 0; r < 16; ++r) OOt[r] = 0.0f;
#pragma unroll
    for (int kk = 0; kk < 4; ++kk) {
      const short8 a = *(const short8*)&ftab[(((2 + rb) * 4 + kk) * 64 + lane) * 8];  // (gr,rb)
      const short8 b = ldrow(&LrU[(cb * 32 + l31) * LSH + kk * 16 + q * 8]);
      OOt = __builtin_amdgcn_mfma_f32_32x32x16_bf16(a, b, OOt, 0, 0, 0);
    }
#pragma unroll
    for (int r = 0; r < 16; ++r) {
      const int jrow = rb * 32 + (r & 3) + 4 * q + 8 * (r >> 2);
      const int icol = cb * 32 + l31;
      Zoo[icol * LSH + jrow] = f2bf(OOt[r] * OOt[r]);  // z_oo[i][j]
    }
    __syncthreads();  // B5

    // ---- P4: Ut = z_oeT + M^T z_ooT ; W = z_eo*M ; Ut -> LrU direct ----
    f32x16 Ut, Wv;
#pragma unroll
    for (int r = 0; r < 16; ++r) { Ut[r] = zoe[r]; Wv[r] = 0.0f; }
#pragma unroll
    for (int kk = 0; kk < 4; ++kk) {
      const short8 aU = *(const short8*)&ftab[(((0 + rb) * 4 + kk) * 64 + lane) * 8];  // (g,rb)
      const short8 bU = ldrow(&Zoo[(cb * 32 + l31) * LSH + kk * 16 + q * 8]);
      Ut = __builtin_amdgcn_mfma_f32_32x32x16_bf16(aU, bU, Ut, 0, 0, 0);
      const short8 aW = ldrow(&XcZ[(rb * 32 + l31) * LSH + kk * 16 + q * 8]);  // z_eo rows
      const short8 bW = *(const short8*)&ftab[(((0 + cb) * 4 + kk) * 64 + lane) * 8];  // (g,cb)
      Wv = __builtin_amdgcn_mfma_f32_32x32x16_bf16(aW, bW, Wv, 0, 0, 0);
    }
#pragma unroll
    for (int r = 0; r < 16; ++r) {
      const int jrow = rb * 32 + (r & 3) + 4 * q + 8 * (r >> 2);
      const int icol = cb * 32 + l31;
      LrU[jrow * LSH + icol] = f2bf(Ut[r]);  // U^T row-major (rows=j)
    }
    __syncthreads();  // B6

    // ---- P5: V = M^T U ; epilogue (x from regs; no global/Xr re-read) ----
    f32x16 Vv;
#pragma unroll
    for (int r = 0; r < 16; ++r) Vv[r] = 0.0f;
#pragma unroll
    for (int kk = 0; kk < 4; ++kk) {
      const short8 a = *(const short8*)&ftab[(((0 + rb) * 4 + kk) * 64 + lane) * 8];  // (g,rb)
      const short8 b = ldrow(&LrU[(cb * 32 + l31) * LSH + kk * 16 + q * 8]);
      Vv = __builtin_amdgcn_mfma_f32_32x32x16_bf16(a, b, Vv, 0, 0, 0);
    }

#pragma unroll
    for (int r = 0; r < 16; ++r) {
      const int irow = rb * 32 + (r & 3) + 4 * q + 8 * (r >> 2);
      const float sgi = (irow & 1) ? -1.0f : 1.0f;
      const float sgj = (jcol & 1) ? -1.0f : 1.0f;
      const float xv_ = bf2f(f2bf(xcur[r]));  // bit-identical to Xr round-trip
      const float vee = xv_ + (sgi * tvec[jcol] + uvec[irow] * sgj) * (1.0f / 64.0f) +
                        sgi * sgj * sigv * (1.0f / 4096.0f);
      const float zee = vee * vee;
      ob[irow * 64 + jcol] = c0 + c1 * xcur[r] + c2q * (zee + Vv[r] + Wv[r]);
    }
    // no loop-end barrier: next P0 writes only Xr/XcZ (not read after B6);
    // tvec/uvec/sigv rewrites happen after next B1.
    if (ci + 1 < cnt) {
#pragma unroll
      for (int r = 0; r < 16; ++r) xcur[r] = xnxt[r];
    }
  }
}

extern "C" void kernel_launch(void* const* d_in, const int* in_sizes, int n_in,
                              void* d_out, int out_size, void* d_ws,
                              size_t ws_size, hipStream_t stream) {
  const float* x = (const float*)d_in[0];
  const float* coef = (const float*)d_in[1];
  float* out = (float*)d_out;
  const int channels = out_size / 4096;  // 32*128 channels of 64x64
  int grid = 768;  // exactly 3 blocks/CU x 256 CU resident -> no block-wave tail
  if (grid > channels) grid = channels;
  uppolyact_kernel<<<dim3(grid), dim3(256), 0, stream>>>(x, coef, out, channels);
}

// Round 3
// 142.782 us; speedup vs baseline: 1.7284x; 1.7284x over previous
//
#include <hip/hip_runtime.h>
#include <math.h>

// UpPolyAct: out = c0 + c1*x + 0.25*c2*( z_ee + V + W )
//   R = X M^T, L = M X, OO = L M^T
//   z_eo=(R+corr)^2, z_oe=(L+corr)^2, z_oo=OO^2, z_ee=(E X E)^2
//   U = z_oe + z_oo M,  V = M^T U,  W = z_eo M
// MFMA plan (32x32x16 bf16, 1 tile/wave, T-domain through U):
//   Rt = M X^T        A=tab(gr,rb)  B=Xr rows
//   Lt = X^T M^T      A=Xc rows     B=tab(gr,cb)
//   OOt = M Lt        A=tab(gr,rb)  B=Lr rows      (Lr = L row-major, T-write)
//   Ut = zoeT + M^T zooT   A=tab(g,rb)  B=Zoo rows (acc init = z_oeT regs)
//   W  = z_eo M       A=Zeo rows    B=tab(g,cb)    (untransposed)
//   V  = M^T U        A=tab(g,rb)   B=UtR rows     (untransposed)
//
// R3: REVERT to baseline structure (grid=4096, 1 channel/block — the block
// scheduler provides 3-deep per-CU pipelining that persistent blocks broke).
// Keep only the phase-internal wins proven in R1/R2:
//  - x loaded once in fragment order into regs (issued FIRST, latency hidden
//    under the g64 cosf build); epilogue uses held regs (no global re-read)
//  - M1 tvec/uvec: all 256 threads, short8 vector loads + shfl_xor reduce
//  - M2 sRv/Luv: all 256 threads, 32 iters; sigv: wave-0 butterfly

typedef short short8 __attribute__((ext_vector_type(8)));
typedef float f32x16 __attribute__((ext_vector_type(16)));

#define LSH 68  // bf16 LDS row stride (68 shorts = 136 B, rows 8B-aligned)

__device__ __forceinline__ short f2bf(float f) {
  unsigned u = __float_as_uint(f);
  u += 0x7FFFu + ((u >> 16) & 1u);
  return (short)(u >> 16);
}
__device__ __forceinline__ float bf2f(short s) {
  return __uint_as_float(((unsigned)(unsigned short)s) << 16);
}
__device__ __forceinline__ short8 ldrow(const short* p) {
  union { unsigned u[4]; short8 s; } v;
  const uint2 lo = *(const uint2*)p;
  const uint2 hi = *(const uint2*)(p + 4);
  v.u[0] = lo.x; v.u[1] = lo.y; v.u[2] = hi.x; v.u[3] = hi.y;
  return v.s;
}

__global__ __launch_bounds__(256, 3) void uppolyact_kernel(
    const float* __restrict__ x, const float* __restrict__ coef,
    float* __restrict__ out) {
  __shared__ __align__(16) short Xr[64 * LSH];    // X row-major bf16
  __shared__ __align__(16) short XcZ[64 * LSH];   // X^T row-major, then z_eo row-major
  __shared__ __align__(16) short LrU[64 * LSH];   // L row-major, then U^T row-major
  __shared__ __align__(16) short Zoo[64 * LSH];   // z_oo row-major
  __shared__ __align__(16) short ftab[16 * 64 * 8];  // M fragments, slot=(t*2+blk)*4+kk
  __shared__ float g64[64];
  __shared__ float tvec[64], uvec[64], sRv[64], Luv[64];
  __shared__ float sigv;

  const int tid = threadIdx.x;
  const int lane = tid & 63;
  const int w = tid >> 6;
  const int q = lane >> 5;
  const int l31 = lane & 31;
  const int rb = w >> 1, cb = w & 1;
  const int jcol = cb * 32 + l31;  // this thread's fixed output column
  const size_t base = (size_t)blockIdx.x * 4096;
  const float* xb = x + base;

  // ---- issue x loads FIRST (fragment order); latency hidden by table build
  float xcur[16];
#pragma unroll
  for (int r = 0; r < 16; ++r) {
    const int irow = rb * 32 + (r & 3) + 4 * q + 8 * (r >> 2);
    xcur[r] = xb[irow * 64 + jcol];
  }

  // ---- g table (bit-identical to baseline) ----
  if (tid < 64) {
    const int d = 2 * tid + 1;
    float s = 1.0f;
    for (int k = 1; k <= 32; ++k) {
      const int qq = (k * d) & 127;
      s += 2.0f * cosf((float)M_PI * (1.0f / 64.0f) * (float)qq);
    }
    g64[tid] = s * (1.0f / 64.0f);
  }

  // ---- P0: xcur regs -> Xr + Xc (bf16) ----
#pragma unroll
  for (int r = 0; r < 16; ++r) {
    const int irow = rb * 32 + (r & 3) + 4 * q + 8 * (r >> 2);
    const short bv = f2bf(xcur[r]);
    Xr[irow * LSH + jcol] = bv;
    XcZ[jcol * LSH + irow] = bv;
  }
  __syncthreads();  // B1: g64 + Xr/XcZ published

  // ---- Phase B: ftab build (reads g64) + M1 tvec/uvec (reads Xr/XcZ) ----
#pragma unroll
  for (int e = 0; e < 4; ++e) {
    const int entry = tid + 256 * e;  // 0..1023
    const int s_ = entry >> 6, ln = entry & 63;
    const int t_ = s_ >> 3, blk = (s_ >> 2) & 1, kk = s_ & 3;
    const int basei = kk * 16 + (ln >> 5) * 8 - (ln & 31) - 32 * blk;
    short* dst = &ftab[(s_ * 64 + ln) * 8];
#pragma unroll
    for (int j = 0; j < 8; ++j) {
      const int i0 = basei + j;
      const int idx = t_ ? ((-i0) & 63) : (i0 & 63);
      dst[j] = f2bf(g64[idx]);
    }
  }
  {
    // tvec[j] = sum_i sign_i X[i][j] (rows of XcZ); uvec[i] = sum_j X[i][j] sign_j (rows of Xr)
    const int o = tid >> 1, h = tid & 1;  // o: output 0..127, h: half
    const short* src = (o < 64) ? &XcZ[o * LSH + 32 * h]
                                : &Xr[(o - 64) * LSH + 32 * h];
    float acc = 0.0f;
#pragma unroll
    for (int p = 0; p < 4; ++p) {
      const short8 v = ldrow(src + 8 * p);
#pragma unroll
      for (int j = 0; j < 8; ++j) {
        const float f = bf2f(v[j]);
        acc += (j & 1) ? -f : f;  // element index 32h+8p+j, parity = j&1
      }
    }
    acc += __shfl_xor(acc, 1);
    if (h == 0) {
      if (o < 64) tvec[o] = acc; else uvec[o - 64] = acc;
    }
  }
  __syncthreads();  // B2: ftab + tvec/uvec published

  // ---- Phase C: MFMA Rt, Lt + M2 sRv/Luv + sigv ----
  f32x16 Rt, Lt;
#pragma unroll
  for (int r = 0; r < 16; ++r) { Rt[r] = 0.0f; Lt[r] = 0.0f; }
#pragma unroll
  for (int kk = 0; kk < 4; ++kk) {
    const short8 aR = *(const short8*)&ftab[(((2 + rb) * 4 + kk) * 64 + lane) * 8];  // (gr,rb)
    const short8 bR = ldrow(&Xr[(cb * 32 + l31) * LSH + kk * 16 + q * 8]);
    Rt = __builtin_amdgcn_mfma_f32_32x32x16_bf16(aR, bR, Rt, 0, 0, 0);
    const short8 aL = ldrow(&XcZ[(rb * 32 + l31) * LSH + kk * 16 + q * 8]);
    const short8 bL = *(const short8*)&ftab[(((2 + cb) * 4 + kk) * 64 + lane) * 8];  // (gr,cb)
    Lt = __builtin_amdgcn_mfma_f32_32x32x16_bf16(aL, bL, Lt, 0, 0, 0);
  }
  {
    // sRv[j] = sum_m tvec[m]*g64[(j-m)&63] ; Luv[i] = sum_m g64[(i-m)&63]*uvec[m]
    const int o = tid >> 1, h = tid & 1;
    const int o63 = o & 63;
    const float* vsrc = (o < 64) ? tvec : uvec;  // wave-uniform select
    float acc = 0.0f;
#pragma unroll
    for (int p = 0; p < 32; ++p) {
      const int m = 32 * h + p;
      acc += vsrc[m] * g64[(o63 - m) & 63];
    }
    acc += __shfl_xor(acc, 1);
    if (h == 0) {
      if (o < 64) sRv[o] = acc; else Luv[o - 64] = acc;
    }
  }
  if (w == 0) {  // sigv = s^T X s = sum_j sign_j * tvec[j]
    float sv = (lane & 1) ? -tvec[lane] : tvec[lane];
#pragma unroll
    for (int d_ = 1; d_ < 64; d_ <<= 1) sv += __shfl_xor(sv, d_);
    if (lane == 0) sigv = sv;
  }
  __syncthreads();  // B3

  // ---- P2: z_eoT -> XcZ (T-write), Lt -> LrU (T-write), z_oeT regs ----
  float zoe[16];
#pragma unroll
  for (int r = 0; r < 16; ++r) {
    const int jrow = rb * 32 + (r & 3) + 4 * q + 8 * (r >> 2);
    const int icol = cb * 32 + l31;
    const float sgi = (icol & 1) ? -1.0f : 1.0f;
    const float sgj = (jrow & 1) ? -1.0f : 1.0f;
    const float veo = Rt[r] + sgi * sRv[jrow] * (1.0f / 64.0f);
    XcZ[icol * LSH + jrow] = f2bf(veo * veo);   // z_eo[i][j]
    LrU[icol * LSH + jrow] = f2bf(Lt[r]);       // L[i][j]
    const float voe = Lt[r] + Luv[icol] * sgj * (1.0f / 64.0f);
    zoe[r] = voe * voe;                         // z_oeT[j][i] (C-layout)
  }
  __syncthreads();  // B4

  // ---- P3: OOt = M*Lt ; z_oo -> Zoo (T-write) ----
  f32x16 OOt;
#pragma unroll
  for (int r = 0; r < 16; ++r) OOt[r] = 0.0f;
#pragma unroll
  for (int kk = 0; kk < 4; ++kk) {
    const short8 a = *(const short8*)&ftab[(((2 + rb) * 4 + kk) * 64 + lane) * 8];  // (gr,rb)
    const short8 b = ldrow(&LrU[(cb * 32 + l31) * LSH + kk * 16 + q * 8]);
    OOt = __builtin_amdgcn_mfma_f32_32x32x16_bf16(a, b, OOt, 0, 0, 0);
  }
#pragma unroll
  for (int r = 0; r < 16; ++r) {
    const int jrow = rb * 32 + (r & 3) + 4 * q + 8 * (r >> 2);
    const int icol = cb * 32 + l31;
    Zoo[icol * LSH + jrow] = f2bf(OOt[r] * OOt[r]);  // z_oo[i][j]
  }
  __syncthreads();  // B5

  // ---- P4: Ut = z_oeT + M^T z_ooT ; W = z_eo*M ; Ut -> LrU direct ----
  f32x16 Ut, Wv;
#pragma unroll
  for (int r = 0; r < 16; ++r) { Ut[r] = zoe[r]; Wv[r] = 0.0f; }
#pragma unroll
  for (int kk = 0; kk < 4; ++kk) {
    const short8 aU = *(const short8*)&ftab[(((0 + rb) * 4 + kk) * 64 + lane) * 8];  // (g,rb)
    const short8 bU = ldrow(&Zoo[(cb * 32 + l31) * LSH + kk * 16 + q * 8]);
    Ut = __builtin_amdgcn_mfma_f32_32x32x16_bf16(aU, bU, Ut, 0, 0, 0);
    const short8 aW = ldrow(&XcZ[(rb * 32 + l31) * LSH + kk * 16 + q * 8]);  // z_eo rows
    const short8 bW = *(const short8*)&ftab[(((0 + cb) * 4 + kk) * 64 + lane) * 8];  // (g,cb)
    Wv = __builtin_amdgcn_mfma_f32_32x32x16_bf16(aW, bW, Wv, 0, 0, 0);
  }
#pragma unroll
  for (int r = 0; r < 16; ++r) {
    const int jrow = rb * 32 + (r & 3) + 4 * q + 8 * (r >> 2);
    const int icol = cb * 32 + l31;
    LrU[jrow * LSH + icol] = f2bf(Ut[r]);  // U^T row-major (rows=j)
  }
  __syncthreads();  // B6

  // ---- P5: V = M^T U ; epilogue (x from regs; no global/Xr re-read) ----
  f32x16 Vv;
#pragma unroll
  for (int r = 0; r < 16; ++r) Vv[r] = 0.0f;
#pragma unroll
  for (int kk = 0; kk < 4; ++kk) {
    const short8 a = *(const short8*)&ftab[(((0 + rb) * 4 + kk) * 64 + lane) * 8];  // (g,rb)
    const short8 b = ldrow(&LrU[(cb * 32 + l31) * LSH + kk * 16 + q * 8]);
    Vv = __builtin_amdgcn_mfma_f32_32x32x16_bf16(a, b, Vv, 0, 0, 0);
  }

  const float c0 = coef[0], c1 = coef[1];
  const float c2q = 0.25f * coef[2];
  float* ob = out + base;
#pragma unroll
  for (int r = 0; r < 16; ++r) {
    const int irow = rb * 32 + (r & 3) + 4 * q + 8 * (r >> 2);
    const float sgi = (irow & 1) ? -1.0f : 1.0f;
    const float sgj = (jcol & 1) ? -1.0f : 1.0f;
    const float xv_ = bf2f(f2bf(xcur[r]));  // bit-identical to Xr round-trip
    const float vee = xv_ + (sgi * tvec[jcol] + uvec[irow] * sgj) * (1.0f / 64.0f) +
                      sgi * sgj * sigv * (1.0f / 4096.0f);
    const float zee = vee * vee;
    ob[irow * 64 + jcol] = c0 + c1 * xcur[r] + c2q * (zee + Vv[r] + Wv[r]);
  }
}

extern "C" void kernel_launch(void* const* d_in, const int* in_sizes, int n_in,
                              void* d_out, int out_size, void* d_ws,
                              size_t ws_size, hipStream_t stream) {
  const float* x = (const float*)d_in[0];
  const float* coef = (const float*)d_in[1];
  float* out = (float*)d_out;
  const int channels = out_size / 4096;  // 32*128 channels of 64x64
  uppolyact_kernel<<<dim3(channels), dim3(256), 0, stream>>>(x, coef, out);
}

// Round 4
// 133.196 us; speedup vs baseline: 1.8528x; 1.0720x over previous
//
#include <hip/hip_runtime.h>
#include <math.h>

// UpPolyAct: out = c0 + c1*x + 0.25*c2*( z_ee + V + W )
//   R = X M^T, L = M X, OO = L M^T
//   z_eo=(R+corr)^2, z_oe=(L+corr)^2, z_oo=OO^2, z_ee=(E X E)^2
//   U = z_oe + z_oo M,  V = M^T U,  W = z_eo M
// MFMA plan (32x32x16 bf16, 1 tile/wave, T-domain through U):
//   Rt = M X^T        A=tab(gr,rb)  B=Xr rows
//   Lt = X^T M^T      A=Xc rows     B=tab(gr,cb)
//   OOt = M Lt        A=tab(gr,rb)  B=Lr rows      (Lr = L row-major, T-write)
//   Ut = zoeT + M^T zooT   A=tab(g,rb)  B=Zoo rows (acc init = z_oeT regs)
//   W  = z_eo M       A=Zeo rows    B=tab(g,cb)    (untransposed)
//   V  = M^T U        A=tab(g,rb)   B=UtR rows     (untransposed)
//
// R4 changes vs R3 (keeps grid=4096, 1 ch/block structure):
//  - g64 + ftab precomputed ONCE into workspace by a flag-guarded 1-WG setup
//    kernel; main kernel copies ftab via 4x dwordx4 -> ds_write_b128 and g64
//    via 64 loads. Removes per-block cosf chain + ~250 VALU + 64 scalar LDS
//    ops/thread. Math in setup is byte-identical -> results unchanged.
//  - adjacent bf16 LDS writes packed: P0 XcZ, P2 XcZ/LrU, P3 Zoo go
//    16x ds_write_b16 -> 4x ds_write_b64 (groups of 4 consecutive rows,
//    8B-aligned: LSH=68, row base multiple of 4).
//  - template<PRE> fallback (= R3 in-block build) if ws too small.

typedef short short8 __attribute__((ext_vector_type(8)));
typedef float f32x16 __attribute__((ext_vector_type(16)));

#define LSH 68  // bf16 LDS row stride (68 shorts = 136 B, rows 8B-aligned)

__device__ __forceinline__ short f2bf(float f) {
  unsigned u = __float_as_uint(f);
  u += 0x7FFFu + ((u >> 16) & 1u);
  return (short)(u >> 16);
}
__device__ __forceinline__ float bf2f(short s) {
  return __uint_as_float(((unsigned)(unsigned short)s) << 16);
}
__device__ __forceinline__ short8 ldrow(const short* p) {
  union { unsigned u[4]; short8 s; } v;
  const uint2 lo = *(const uint2*)p;
  const uint2 hi = *(const uint2*)(p + 4);
  v.u[0] = lo.x; v.u[1] = lo.y; v.u[2] = hi.x; v.u[3] = hi.y;
  return v.s;
}
__device__ __forceinline__ unsigned pk2(short a, short b) {
  return (unsigned)(unsigned short)a | ((unsigned)(unsigned short)b << 16);
}

// ---- setup: build g64 (64 f32) + ftab (16*64*8 bf16) into workspace ----
__global__ void uppolyact_setup(unsigned* __restrict__ flag,
                                float* __restrict__ gws,
                                short* __restrict__ ftw) {
  if (*flag == 0xC0FFEEu) return;  // uniform read; replays early-out
  __shared__ float g64s[64];
  const int tid = threadIdx.x;
  if (tid < 64) {
    const int d = 2 * tid + 1;
    float s = 1.0f;
    for (int k = 1; k <= 32; ++k) {
      const int qq = (k * d) & 127;
      s += 2.0f * cosf((float)M_PI * (1.0f / 64.0f) * (float)qq);
    }
    const float gv = s * (1.0f / 64.0f);
    g64s[tid] = gv;
    gws[tid] = gv;
  }
  __syncthreads();
#pragma unroll
  for (int e = 0; e < 4; ++e) {
    const int entry = tid + 256 * e;  // 0..1023
    const int s_ = entry >> 6, ln = entry & 63;
    const int t_ = s_ >> 3, blk = (s_ >> 2) & 1, kk = s_ & 3;
    const int basei = kk * 16 + (ln >> 5) * 8 - (ln & 31) - 32 * blk;
    short* dst = &ftw[(s_ * 64 + ln) * 8];
#pragma unroll
    for (int j = 0; j < 8; ++j) {
      const int i0 = basei + j;
      const int idx = t_ ? ((-i0) & 63) : (i0 & 63);
      dst[j] = f2bf(g64s[idx]);
    }
  }
  __syncthreads();
  if (tid == 0) *flag = 0xC0FFEEu;
}

template <bool PRE>
__global__ __launch_bounds__(256, 3) void uppolyact_kernel(
    const float* __restrict__ x, const float* __restrict__ coef,
    float* __restrict__ out, const float* __restrict__ gws,
    const short* __restrict__ ftw) {
  __shared__ __align__(16) short Xr[64 * LSH];    // X row-major bf16
  __shared__ __align__(16) short XcZ[64 * LSH];   // X^T row-major, then z_eo row-major
  __shared__ __align__(16) short LrU[64 * LSH];   // L row-major, then U^T row-major
  __shared__ __align__(16) short Zoo[64 * LSH];   // z_oo row-major
  __shared__ __align__(16) short ftab[16 * 64 * 8];  // M fragments, slot=(t*2+blk)*4+kk
  __shared__ float g64[64];
  __shared__ float tvec[64], uvec[64], sRv[64], Luv[64];
  __shared__ float sigv;

  const int tid = threadIdx.x;
  const int lane = tid & 63;
  const int w = tid >> 6;
  const int q = lane >> 5;
  const int l31 = lane & 31;
  const int rb = w >> 1, cb = w & 1;
  const int jcol = cb * 32 + l31;  // this thread's fixed output column
  const size_t base = (size_t)blockIdx.x * 4096;
  const float* xb = x + base;

  // ---- issue x loads FIRST (fragment order) ----
  float xcur[16];
#pragma unroll
  for (int r = 0; r < 16; ++r) {
    const int irow = rb * 32 + (r & 3) + 4 * q + 8 * (r >> 2);
    xcur[r] = xb[irow * 64 + jcol];
  }

  float4 t0, t1, t2, t3;
  if (PRE) {
    // issue ftab copy loads (hot in L2/L3: same 16 KB for all blocks)
    const float4* fsrc = (const float4*)ftw;
    t0 = fsrc[tid];
    t1 = fsrc[tid + 256];
    t2 = fsrc[tid + 512];
    t3 = fsrc[tid + 768];
    if (tid < 64) g64[tid] = gws[tid];
  } else {
    // g table (bit-identical to baseline)
    if (tid < 64) {
      const int d = 2 * tid + 1;
      float s = 1.0f;
      for (int k = 1; k <= 32; ++k) {
        const int qq = (k * d) & 127;
        s += 2.0f * cosf((float)M_PI * (1.0f / 64.0f) * (float)qq);
      }
      g64[tid] = s * (1.0f / 64.0f);
    }
  }

  // ---- P0: xcur regs -> Xr (scalar) + XcZ (packed b64) ----
#pragma unroll
  for (int k = 0; k < 4; ++k) {
    const int irowb = rb * 32 + 4 * q + 8 * k;  // irow = irowb + j, j=0..3
    short b[4];
#pragma unroll
    for (int j = 0; j < 4; ++j) {
      b[j] = f2bf(xcur[4 * k + j]);
      Xr[(irowb + j) * LSH + jcol] = b[j];
    }
    uint2 p;
    p.x = pk2(b[0], b[1]);
    p.y = pk2(b[2], b[3]);
    *(uint2*)&XcZ[jcol * LSH + irowb] = p;
  }
  if (PRE) {
    float4* fdst = (float4*)ftab;
    fdst[tid] = t0;
    fdst[tid + 256] = t1;
    fdst[tid + 512] = t2;
    fdst[tid + 768] = t3;
  }
  __syncthreads();  // B1: g64 + Xr/XcZ (+ftab if PRE) published

  // ---- Phase B: (ftab build if !PRE) + M1 tvec/uvec ----
  if (!PRE) {
#pragma unroll
    for (int e = 0; e < 4; ++e) {
      const int entry = tid + 256 * e;  // 0..1023
      const int s_ = entry >> 6, ln = entry & 63;
      const int t_ = s_ >> 3, blk = (s_ >> 2) & 1, kk = s_ & 3;
      const int basei = kk * 16 + (ln >> 5) * 8 - (ln & 31) - 32 * blk;
      short* dst = &ftab[(s_ * 64 + ln) * 8];
#pragma unroll
      for (int j = 0; j < 8; ++j) {
        const int i0 = basei + j;
        const int idx = t_ ? ((-i0) & 63) : (i0 & 63);
        dst[j] = f2bf(g64[idx]);
      }
    }
  }
  {
    // tvec[j] = sum_i sign_i X[i][j] (rows of XcZ); uvec[i] = sum_j X[i][j] sign_j (rows of Xr)
    const int o = tid >> 1, h = tid & 1;  // o: output 0..127, h: half
    const short* src = (o < 64) ? &XcZ[o * LSH + 32 * h]
                                : &Xr[(o - 64) * LSH + 32 * h];
    float acc = 0.0f;
#pragma unroll
    for (int p = 0; p < 4; ++p) {
      const short8 v = ldrow(src + 8 * p);
#pragma unroll
      for (int j = 0; j < 8; ++j) {
        const float f = bf2f(v[j]);
        acc += (j & 1) ? -f : f;  // element index 32h+8p+j, parity = j&1
      }
    }
    acc += __shfl_xor(acc, 1);
    if (h == 0) {
      if (o < 64) tvec[o] = acc; else uvec[o - 64] = acc;
    }
  }
  __syncthreads();  // B2: ftab + tvec/uvec published

  // ---- Phase C: MFMA Rt, Lt + M2 sRv/Luv + sigv ----
  f32x16 Rt, Lt;
#pragma unroll
  for (int r = 0; r < 16; ++r) { Rt[r] = 0.0f; Lt[r] = 0.0f; }
#pragma unroll
  for (int kk = 0; kk < 4; ++kk) {
    const short8 aR = *(const short8*)&ftab[(((2 + rb) * 4 + kk) * 64 + lane) * 8];  // (gr,rb)
    const short8 bR = ldrow(&Xr[(cb * 32 + l31) * LSH + kk * 16 + q * 8]);
    Rt = __builtin_amdgcn_mfma_f32_32x32x16_bf16(aR, bR, Rt, 0, 0, 0);
    const short8 aL = ldrow(&XcZ[(rb * 32 + l31) * LSH + kk * 16 + q * 8]);
    const short8 bL = *(const short8*)&ftab[(((2 + cb) * 4 + kk) * 64 + lane) * 8];  // (gr,cb)
    Lt = __builtin_amdgcn_mfma_f32_32x32x16_bf16(aL, bL, Lt, 0, 0, 0);
  }
  {
    // sRv[j] = sum_m tvec[m]*g64[(j-m)&63] ; Luv[i] = sum_m g64[(i-m)&63]*uvec[m]
    const int o = tid >> 1, h = tid & 1;
    const int o63 = o & 63;
    const float* vsrc = (o < 64) ? tvec : uvec;  // wave-uniform select
    float acc = 0.0f;
#pragma unroll
    for (int p = 0; p < 32; ++p) {
      const int m = 32 * h + p;
      acc += vsrc[m] * g64[(o63 - m) & 63];
    }
    acc += __shfl_xor(acc, 1);
    if (h == 0) {
      if (o < 64) sRv[o] = acc; else Luv[o - 64] = acc;
    }
  }
  if (w == 0) {  // sigv = s^T X s = sum_j sign_j * tvec[j]
    float sv = (lane & 1) ? -tvec[lane] : tvec[lane];
#pragma unroll
    for (int d_ = 1; d_ < 64; d_ <<= 1) sv += __shfl_xor(sv, d_);
    if (lane == 0) sigv = sv;
  }
  __syncthreads();  // B3

  // ---- P2: z_eoT -> XcZ (packed), Lt -> LrU (packed), z_oeT regs ----
  float zoe[16];
  {
    const int icol = cb * 32 + l31;
    const float sgi = (icol & 1) ? -1.0f : 1.0f;
#pragma unroll
    for (int k = 0; k < 4; ++k) {
      const int jb = rb * 32 + 4 * q + 8 * k;  // jrow = jb + t, t=0..3
      short ze[4], zl[4];
#pragma unroll
      for (int t = 0; t < 4; ++t) {
        const int r = 4 * k + t;
        const int jrow = jb + t;
        const float sgj = (jrow & 1) ? -1.0f : 1.0f;
        const float veo = Rt[r] + sgi * sRv[jrow] * (1.0f / 64.0f);
        ze[t] = f2bf(veo * veo);               // z_eo[i][j]
        zl[t] = f2bf(Lt[r]);                   // L[i][j]
        const float voe = Lt[r] + Luv[icol] * sgj * (1.0f / 64.0f);
        zoe[r] = voe * voe;                    // z_oeT[j][i] (C-layout)
      }
      uint2 pz, pl;
      pz.x = pk2(ze[0], ze[1]); pz.y = pk2(ze[2], ze[3]);
      pl.x = pk2(zl[0], zl[1]); pl.y = pk2(zl[2], zl[3]);
      *(uint2*)&XcZ[icol * LSH + jb] = pz;
      *(uint2*)&LrU[icol * LSH + jb] = pl;
    }
  }
  __syncthreads();  // B4

  // ---- P3: OOt = M*Lt ; z_oo -> Zoo (packed T-write) ----
  f32x16 OOt;
#pragma unroll
  for (int r = 0; r < 16; ++r) OOt[r] = 0.0f;
#pragma unroll
  for (int kk = 0; kk < 4; ++kk) {
    const short8 a = *(const short8*)&ftab[(((2 + rb) * 4 + kk) * 64 + lane) * 8];  // (gr,rb)
    const short8 b = ldrow(&LrU[(cb * 32 + l31) * LSH + kk * 16 + q * 8]);
    OOt = __builtin_amdgcn_mfma_f32_32x32x16_bf16(a, b, OOt, 0, 0, 0);
  }
  {
    const int icol = cb * 32 + l31;
#pragma unroll
    for (int k = 0; k < 4; ++k) {
      const int jb = rb * 32 + 4 * q + 8 * k;
      short zo[4];
#pragma unroll
      for (int t = 0; t < 4; ++t) {
        const int r = 4 * k + t;
        zo[t] = f2bf(OOt[r] * OOt[r]);
      }
      uint2 p;
      p.x = pk2(zo[0], zo[1]); p.y = pk2(zo[2], zo[3]);
      *(uint2*)&Zoo[icol * LSH + jb] = p;  // z_oo[i][j]
    }
  }
  __syncthreads();  // B5

  // ---- P4: Ut = z_oeT + M^T z_ooT ; W = z_eo*M ; Ut -> LrU direct ----
  f32x16 Ut, Wv;
#pragma unroll
  for (int r = 0; r < 16; ++r) { Ut[r] = zoe[r]; Wv[r] = 0.0f; }
#pragma unroll
  for (int kk = 0; kk < 4; ++kk) {
    const short8 aU = *(const short8*)&ftab[(((0 + rb) * 4 + kk) * 64 + lane) * 8];  // (g,rb)
    const short8 bU = ldrow(&Zoo[(cb * 32 + l31) * LSH + kk * 16 + q * 8]);
    Ut = __builtin_amdgcn_mfma_f32_32x32x16_bf16(aU, bU, Ut, 0, 0, 0);
    const short8 aW = ldrow(&XcZ[(rb * 32 + l31) * LSH + kk * 16 + q * 8]);  // z_eo rows
    const short8 bW = *(const short8*)&ftab[(((0 + cb) * 4 + kk) * 64 + lane) * 8];  // (g,cb)
    Wv = __builtin_amdgcn_mfma_f32_32x32x16_bf16(aW, bW, Wv, 0, 0, 0);
  }
#pragma unroll
  for (int r = 0; r < 16; ++r) {
    const int jrow = rb * 32 + (r & 3) + 4 * q + 8 * (r >> 2);
    const int icol = cb * 32 + l31;
    LrU[jrow * LSH + icol] = f2bf(Ut[r]);  // U^T row-major (rows=j); strided, scalar
  }
  __syncthreads();  // B6

  // ---- P5: V = M^T U ; epilogue (x from regs; no global/Xr re-read) ----
  f32x16 Vv;
#pragma unroll
  for (int r = 0; r < 16; ++r) Vv[r] = 0.0f;
#pragma unroll
  for (int kk = 0; kk < 4; ++kk) {
    const short8 a = *(const short8*)&ftab[(((0 + rb) * 4 + kk) * 64 + lane) * 8];  // (g,rb)
    const short8 b = ldrow(&LrU[(cb * 32 + l31) * LSH + kk * 16 + q * 8]);
    Vv = __builtin_amdgcn_mfma_f32_32x32x16_bf16(a, b, Vv, 0, 0, 0);
  }

  const float c0 = coef[0], c1 = coef[1];
  const float c2q = 0.25f * coef[2];
  float* ob = out + base;
#pragma unroll
  for (int r = 0; r < 16; ++r) {
    const int irow = rb * 32 + (r & 3) + 4 * q + 8 * (r >> 2);
    const float sgi = (irow & 1) ? -1.0f : 1.0f;
    const float sgj = (jcol & 1) ? -1.0f : 1.0f;
    const float xv_ = bf2f(f2bf(xcur[r]));  // bit-identical to Xr round-trip
    const float vee = xv_ + (sgi * tvec[jcol] + uvec[irow] * sgj) * (1.0f / 64.0f) +
                      sgi * sgj * sigv * (1.0f / 4096.0f);
    const float zee = vee * vee;
    ob[irow * 64 + jcol] = c0 + c1 * xcur[r] + c2q * (zee + Vv[r] + Wv[r]);
  }
}

extern "C" void kernel_launch(void* const* d_in, const int* in_sizes, int n_in,
                              void* d_out, int out_size, void* d_ws,
                              size_t ws_size, hipStream_t stream) {
  const float* x = (const float*)d_in[0];
  const float* coef = (const float*)d_in[1];
  float* out = (float*)d_out;
  const int channels = out_size / 4096;  // 32*128 channels of 64x64
  // ws layout: [0..4): flag, [256..512): g64 f32, [512..16896): ftab bf16
  const bool pre = (d_ws != nullptr && ws_size >= 16896);
  if (pre) {
    unsigned* flag = (unsigned*)d_ws;
    float* gws = (float*)((char*)d_ws + 256);
    short* ftw = (short*)((char*)d_ws + 512);
    uppolyact_setup<<<dim3(1), dim3(256), 0, stream>>>(flag, gws, ftw);
    uppolyact_kernel<true><<<dim3(channels), dim3(256), 0, stream>>>(
        x, coef, out, gws, ftw);
  } else {
    uppolyact_kernel<false><<<dim3(channels), dim3(256), 0, stream>>>(
        x, coef, out, nullptr, nullptr);
  }
}

// Round 5
// 126.480 us; speedup vs baseline: 1.9512x; 1.0531x over previous
//
#include <hip/hip_runtime.h>
#include <math.h>

// UpPolyAct: out = c0 + c1*x + 0.25*c2*( z_ee + V + W )
//   R = X M^T, L = M X, OO = L M^T
//   z_eo=(R+corr)^2, z_oe=(L+corr)^2, z_oo=OO^2, z_ee=(E X E)^2
//   U = z_oe + z_oo M,  V = M^T U,  W = z_eo M
// MFMA plan (32x32x16 bf16, 1 tile/wave, T-domain through U):
//   Rt = M X^T        A=tab(gr,rb)  B=Xr rows
//   Lt = X^T M^T      A=Xc rows     B=tab(gr,cb)
//   OOt = M Lt        A=tab(gr,rb)  B=Lr rows      (Lr = L row-major, T-write)
//   Ut = zoeT + M^T zooT   A=tab(g,rb)  B=Zoo rows (acc init = z_oeT regs)
//   W  = z_eo M       A=Zeo rows    B=tab(g,cb)    (untransposed)
//   V  = M^T U        A=tab(g,rb)   B=UtR rows     (untransposed)
//
// R5 changes vs R4:
//  - ftab removed from LDS entirely: MFMA M-fragments are loaded directly
//    from a global device table (L2-resident 16 KB shared by all blocks) into
//    registers one phase ahead of use. LDS 52.7 KB -> 36.3 KB -> 4 blocks/CU
//    (__launch_bounds__(256,4)); removes the per-block ftab copy + its B1
//    vmcnt-drain.
//  - tables live in device globals (.bss), flag-guarded setup kernel; no
//    workspace dependency, single code path. Setup math byte-identical.

typedef short short8 __attribute__((ext_vector_type(8)));
typedef float f32x16 __attribute__((ext_vector_type(16)));

#define LSH 68  // bf16 LDS row stride (68 shorts = 136 B, rows 8B-aligned)

__device__ unsigned g_flag;                      // zero-initialized (.bss)
__device__ float g_gws[64];
__device__ __align__(16) short g_ftw[16 * 64 * 8];  // M fragments, slot=(t*2+blk)*4+kk

__device__ __forceinline__ short f2bf(float f) {
  unsigned u = __float_as_uint(f);
  u += 0x7FFFu + ((u >> 16) & 1u);
  return (short)(u >> 16);
}
__device__ __forceinline__ float bf2f(short s) {
  return __uint_as_float(((unsigned)(unsigned short)s) << 16);
}
__device__ __forceinline__ short8 ldrow(const short* p) {
  union { unsigned u[4]; short8 s; } v;
  const uint2 lo = *(const uint2*)p;
  const uint2 hi = *(const uint2*)(p + 4);
  v.u[0] = lo.x; v.u[1] = lo.y; v.u[2] = hi.x; v.u[3] = hi.y;
  return v.s;
}
__device__ __forceinline__ unsigned pk2(short a, short b) {
  return (unsigned)(unsigned short)a | ((unsigned)(unsigned short)b << 16);
}

// ---- setup: build g64 (64 f32) + ftab (16*64*8 bf16) into device globals ----
__global__ void uppolyact_setup() {
  if (g_flag == 0xC0FFEEu) return;  // replays early-out
  __shared__ float g64s[64];
  const int tid = threadIdx.x;
  if (tid < 64) {
    const int d = 2 * tid + 1;
    float s = 1.0f;
    for (int k = 1; k <= 32; ++k) {
      const int qq = (k * d) & 127;
      s += 2.0f * cosf((float)M_PI * (1.0f / 64.0f) * (float)qq);
    }
    const float gv = s * (1.0f / 64.0f);
    g64s[tid] = gv;
    g_gws[tid] = gv;
  }
  __syncthreads();
#pragma unroll
  for (int e = 0; e < 4; ++e) {
    const int entry = tid + 256 * e;  // 0..1023
    const int s_ = entry >> 6, ln = entry & 63;
    const int t_ = s_ >> 3, blk = (s_ >> 2) & 1, kk = s_ & 3;
    const int basei = kk * 16 + (ln >> 5) * 8 - (ln & 31) - 32 * blk;
    short* dst = &g_ftw[(s_ * 64 + ln) * 8];
#pragma unroll
    for (int j = 0; j < 8; ++j) {
      const int i0 = basei + j;
      const int idx = t_ ? ((-i0) & 63) : (i0 & 63);
      dst[j] = f2bf(g64s[idx]);
    }
  }
  __syncthreads();
  if (tid == 0) g_flag = 0xC0FFEEu;
}

__global__ __launch_bounds__(256, 4) void uppolyact_kernel(
    const float* __restrict__ x, const float* __restrict__ coef,
    float* __restrict__ out) {
  __shared__ __align__(16) short Xr[64 * LSH];    // X row-major bf16
  __shared__ __align__(16) short XcZ[64 * LSH];   // X^T row-major, then z_eo row-major
  __shared__ __align__(16) short LrU[64 * LSH];   // L row-major, then U^T row-major
  __shared__ __align__(16) short Zoo[64 * LSH];   // z_oo row-major
  __shared__ float g64[64];
  __shared__ float tvec[64], uvec[64], sRv[64], Luv[64];
  __shared__ float sigv;

  const int tid = threadIdx.x;
  const int lane = tid & 63;
  const int w = tid >> 6;
  const int q = lane >> 5;
  const int l31 = lane & 31;
  const int rb = w >> 1, cb = w & 1;
  const int jcol = cb * 32 + l31;  // this thread's fixed output column
  const size_t base = (size_t)blockIdx.x * 4096;
  const float* xb = x + base;
  const short8* ft8 = (const short8*)g_ftw;

  // ---- issue x loads FIRST (fragment order) ----
  float xcur[16];
#pragma unroll
  for (int r = 0; r < 16; ++r) {
    const int irow = rb * 32 + (r & 3) + 4 * q + 8 * (r >> 2);
    xcur[r] = xb[irow * 64 + jcol];
  }

  // ---- prefetch phase-C fragments from global (L2-hot, coalesced 1KB/wave)
  // fA = (gr,rb) slots (also reused by P3 OOt); fB = (gr,cb) slots
  short8 fA[4], fB[4];
#pragma unroll
  for (int kk = 0; kk < 4; ++kk) {
    fA[kk] = ft8[((2 + rb) * 4 + kk) * 64 + lane];
    fB[kk] = ft8[((2 + cb) * 4 + kk) * 64 + lane];
  }
  if (tid < 64) g64[tid] = g_gws[tid];

  // ---- P0: xcur regs -> Xr (scalar) + XcZ (packed b64) ----
#pragma unroll
  for (int k = 0; k < 4; ++k) {
    const int irowb = rb * 32 + 4 * q + 8 * k;  // irow = irowb + j, j=0..3
    short b[4];
#pragma unroll
    for (int j = 0; j < 4; ++j) {
      b[j] = f2bf(xcur[4 * k + j]);
      Xr[(irowb + j) * LSH + jcol] = b[j];
    }
    uint2 p;
    p.x = pk2(b[0], b[1]);
    p.y = pk2(b[2], b[3]);
    *(uint2*)&XcZ[jcol * LSH + irowb] = p;
  }
  __syncthreads();  // B1: g64 + Xr/XcZ published

  // ---- M1 tvec/uvec (all 256 threads, vectorized) ----
  {
    // tvec[j] = sum_i sign_i X[i][j] (rows of XcZ); uvec[i] = sum_j X[i][j] sign_j (rows of Xr)
    const int o = tid >> 1, h = tid & 1;  // o: output 0..127, h: half
    const short* src = (o < 64) ? &XcZ[o * LSH + 32 * h]
                                : &Xr[(o - 64) * LSH + 32 * h];
    float acc = 0.0f;
#pragma unroll
    for (int p = 0; p < 4; ++p) {
      const short8 v = ldrow(src + 8 * p);
#pragma unroll
      for (int j = 0; j < 8; ++j) {
        const float f = bf2f(v[j]);
        acc += (j & 1) ? -f : f;  // element index 32h+8p+j, parity = j&1
      }
    }
    acc += __shfl_xor(acc, 1);
    if (h == 0) {
      if (o < 64) tvec[o] = acc; else uvec[o - 64] = acc;
    }
  }
  __syncthreads();  // B2: tvec/uvec published

  // ---- Phase C: MFMA Rt, Lt (frags from regs) + M2 sRv/Luv + sigv ----
  f32x16 Rt, Lt;
#pragma unroll
  for (int r = 0; r < 16; ++r) { Rt[r] = 0.0f; Lt[r] = 0.0f; }
#pragma unroll
  for (int kk = 0; kk < 4; ++kk) {
    const short8 bR = ldrow(&Xr[(cb * 32 + l31) * LSH + kk * 16 + q * 8]);
    Rt = __builtin_amdgcn_mfma_f32_32x32x16_bf16(fA[kk], bR, Rt, 0, 0, 0);
    const short8 aL = ldrow(&XcZ[(rb * 32 + l31) * LSH + kk * 16 + q * 8]);
    Lt = __builtin_amdgcn_mfma_f32_32x32x16_bf16(aL, fB[kk], Lt, 0, 0, 0);
  }
  {
    // sRv[j] = sum_m tvec[m]*g64[(j-m)&63] ; Luv[i] = sum_m g64[(i-m)&63]*uvec[m]
    const int o = tid >> 1, h = tid & 1;
    const int o63 = o & 63;
    const float* vsrc = (o < 64) ? tvec : uvec;  // wave-uniform select
    float acc = 0.0f;
#pragma unroll
    for (int p = 0; p < 32; ++p) {
      const int m = 32 * h + p;
      acc += vsrc[m] * g64[(o63 - m) & 63];
    }
    acc += __shfl_xor(acc, 1);
    if (h == 0) {
      if (o < 64) sRv[o] = acc; else Luv[o - 64] = acc;
    }
  }
  if (w == 0) {  // sigv = s^T X s = sum_j sign_j * tvec[j]
    float sv = (lane & 1) ? -tvec[lane] : tvec[lane];
#pragma unroll
    for (int d_ = 1; d_ < 64; d_ <<= 1) sv += __shfl_xor(sv, d_);
    if (lane == 0) sigv = sv;
  }
  __syncthreads();  // B3

  // ---- P2: z_eoT -> XcZ (packed), Lt -> LrU (packed), z_oeT regs ----
  float zoe[16];
  {
    const int icol = cb * 32 + l31;
    const float sgi = (icol & 1) ? -1.0f : 1.0f;
#pragma unroll
    for (int k = 0; k < 4; ++k) {
      const int jb = rb * 32 + 4 * q + 8 * k;  // jrow = jb + t, t=0..3
      short ze[4], zl[4];
#pragma unroll
      for (int t = 0; t < 4; ++t) {
        const int r = 4 * k + t;
        const int jrow = jb + t;
        const float sgj = (jrow & 1) ? -1.0f : 1.0f;
        const float veo = Rt[r] + sgi * sRv[jrow] * (1.0f / 64.0f);
        ze[t] = f2bf(veo * veo);               // z_eo[i][j]
        zl[t] = f2bf(Lt[r]);                   // L[i][j]
        const float voe = Lt[r] + Luv[icol] * sgj * (1.0f / 64.0f);
        zoe[r] = voe * voe;                    // z_oeT[j][i] (C-layout)
      }
      uint2 pz, pl;
      pz.x = pk2(ze[0], ze[1]); pz.y = pk2(ze[2], ze[3]);
      pl.x = pk2(zl[0], zl[1]); pl.y = pk2(zl[2], zl[3]);
      *(uint2*)&XcZ[icol * LSH + jb] = pz;
      *(uint2*)&LrU[icol * LSH + jb] = pl;
    }
  }
  __syncthreads();  // B4

  // ---- P3: prefetch P4/P5 fragments; OOt = M*Lt ; z_oo -> Zoo (packed) ----
  short8 fU[4], fW[4];  // fU = (g,rb) (used P4 aU + P5 Vv-a); fW = (g,cb)
#pragma unroll
  for (int kk = 0; kk < 4; ++kk) {
    fU[kk] = ft8[((0 + rb) * 4 + kk) * 64 + lane];
    fW[kk] = ft8[((0 + cb) * 4 + kk) * 64 + lane];
  }
  f32x16 OOt;
#pragma unroll
  for (int r = 0; r < 16; ++r) OOt[r] = 0.0f;
#pragma unroll
  for (int kk = 0; kk < 4; ++kk) {
    const short8 b = ldrow(&LrU[(cb * 32 + l31) * LSH + kk * 16 + q * 8]);
    OOt = __builtin_amdgcn_mfma_f32_32x32x16_bf16(fA[kk], b, OOt, 0, 0, 0);
  }
  {
    const int icol = cb * 32 + l31;
#pragma unroll
    for (int k = 0; k < 4; ++k) {
      const int jb = rb * 32 + 4 * q + 8 * k;
      short zo[4];
#pragma unroll
      for (int t = 0; t < 4; ++t) {
        const int r = 4 * k + t;
        zo[t] = f2bf(OOt[r] * OOt[r]);
      }
      uint2 p;
      p.x = pk2(zo[0], zo[1]); p.y = pk2(zo[2], zo[3]);
      *(uint2*)&Zoo[icol * LSH + jb] = p;  // z_oo[i][j]
    }
  }
  __syncthreads();  // B5

  // ---- P4: Ut = z_oeT + M^T z_ooT ; W = z_eo*M ; Ut -> LrU direct ----
  f32x16 Ut, Wv;
#pragma unroll
  for (int r = 0; r < 16; ++r) { Ut[r] = zoe[r]; Wv[r] = 0.0f; }
#pragma unroll
  for (int kk = 0; kk < 4; ++kk) {
    const short8 bU = ldrow(&Zoo[(cb * 32 + l31) * LSH + kk * 16 + q * 8]);
    Ut = __builtin_amdgcn_mfma_f32_32x32x16_bf16(fU[kk], bU, Ut, 0, 0, 0);
    const short8 aW = ldrow(&XcZ[(rb * 32 + l31) * LSH + kk * 16 + q * 8]);  // z_eo rows
    Wv = __builtin_amdgcn_mfma_f32_32x32x16_bf16(aW, fW[kk], Wv, 0, 0, 0);
  }
#pragma unroll
  for (int r = 0; r < 16; ++r) {
    const int jrow = rb * 32 + (r & 3) + 4 * q + 8 * (r >> 2);
    const int icol = cb * 32 + l31;
    LrU[jrow * LSH + icol] = f2bf(Ut[r]);  // U^T row-major (rows=j); strided, scalar
  }
  __syncthreads();  // B6

  // ---- P5: V = M^T U ; epilogue (x from regs; no global/Xr re-read) ----
  f32x16 Vv;
#pragma unroll
  for (int r = 0; r < 16; ++r) Vv[r] = 0.0f;
#pragma unroll
  for (int kk = 0; kk < 4; ++kk) {
    const short8 b = ldrow(&LrU[(cb * 32 + l31) * LSH + kk * 16 + q * 8]);
    Vv = __builtin_amdgcn_mfma_f32_32x32x16_bf16(fU[kk], b, Vv, 0, 0, 0);
  }

  const float c0 = coef[0], c1 = coef[1];
  const float c2q = 0.25f * coef[2];
  float* ob = out + base;
#pragma unroll
  for (int r = 0; r < 16; ++r) {
    const int irow = rb * 32 + (r & 3) + 4 * q + 8 * (r >> 2);
    const float sgi = (irow & 1) ? -1.0f : 1.0f;
    const float sgj = (jcol & 1) ? -1.0f : 1.0f;
    const float xv_ = bf2f(f2bf(xcur[r]));  // bit-identical to Xr round-trip
    const float vee = xv_ + (sgi * tvec[jcol] + uvec[irow] * sgj) * (1.0f / 64.0f) +
                      sgi * sgj * sigv * (1.0f / 4096.0f);
    const float zee = vee * vee;
    ob[irow * 64 + jcol] = c0 + c1 * xcur[r] + c2q * (zee + Vv[r] + Wv[r]);
  }
}

extern "C" void kernel_launch(void* const* d_in, const int* in_sizes, int n_in,
                              void* d_out, int out_size, void* d_ws,
                              size_t ws_size, hipStream_t stream) {
  const float* x = (const float*)d_in[0];
  const float* coef = (const float*)d_in[1];
  float* out = (float*)d_out;
  const int channels = out_size / 4096;  // 32*128 channels of 64x64
  uppolyact_setup<<<dim3(1), dim3(256), 0, stream>>>();
  uppolyact_kernel<<<dim3(channels), dim3(256), 0, stream>>>(x, coef, out);
}